// Round 1
// baseline (1429.124 us; speedup 1.0000x reference)
//
#include <hip/hip_runtime.h>
#include <hip/hip_bf16.h>

// RiemGrassAtt fp32 baseline.
// Shapes: B=32, N=256, H=12, d=64, D=768.
// Pipeline:
//   K1 qkv GEMM (29 GFLOP) -> q,k,v in (t,B,H,N,d) layout
//   K2 CholeskyQR per (t,b,h) slab: Q = A * chol(A^T A)^-1   (sign convention
//      differs from LAPACK Householder by per-column signs; logits are O(1e-5)
//      so this perturbs the output at ~1e-6, far below the 1.9e-3 threshold)
//   K3 logits: mixed[b,o,n,m] = sum_h (cw[o,h]+cw[o,h+12]) * (Qq_n . Qk_m)^2 * scale + cb[o]
//   K4 row softmax (in place)
//   K5 attn @ v -> (B,N,C) layout
//   K6 proj GEMM (9.7 GFLOP) -> d_out

#define B_   32
#define N_   256
#define H_   12
#define D_   768
#define HD   64
#define SLAB (N_ * HD)   // 16384
#define BH   (B_ * H_)   // 384

// ---------------------------------------------------------------------------
// K1: qkv = x @ qkv_w^T + qkv_b, scattered into (3,B,H,N,d)
// 128x128 tile, 256 threads, 8x8 per thread, K-chunks of 16.
// ---------------------------------------------------------------------------
__global__ __launch_bounds__(256) void k_qkv_gemm(const float* __restrict__ x,
                                                  const float* __restrict__ w,
                                                  const float* __restrict__ bias,
                                                  float* __restrict__ qkv) {
    __shared__ float As[128][17];
    __shared__ float Bs[128][17];
    const int tid = threadIdx.x;
    const int r0 = blockIdx.x * 128;
    const int c0 = blockIdx.y * 128;
    const int ty = tid >> 4, tx = tid & 15;
    float acc[8][8] = {};

    for (int k0 = 0; k0 < D_; k0 += 16) {
#pragma unroll
        for (int i = 0; i < 8; i++) {
            int e = i * 256 + tid;
            int row = e >> 4, kk = e & 15;
            As[row][kk] = x[(size_t)(r0 + row) * D_ + k0 + kk];
            Bs[row][kk] = w[(size_t)(c0 + row) * D_ + k0 + kk];
        }
        __syncthreads();
#pragma unroll
        for (int kk = 0; kk < 16; kk++) {
            float a[8], b[8];
#pragma unroll
            for (int i = 0; i < 8; i++) a[i] = As[ty * 8 + i][kk];
#pragma unroll
            for (int j = 0; j < 8; j++) b[j] = Bs[tx * 8 + j][kk];
#pragma unroll
            for (int i = 0; i < 8; i++)
#pragma unroll
                for (int j = 0; j < 8; j++) acc[i][j] += a[i] * b[j];
        }
        __syncthreads();
    }

#pragma unroll
    for (int i = 0; i < 8; i++) {
        int r = r0 + ty * 8 + i;
        int b_ = r >> 8, n = r & 255;
#pragma unroll
        for (int j = 0; j < 8; j++) {
            int c = c0 + tx * 8 + j;
            float v = acc[i][j] + bias[c];
            int t = c / D_;
            int rem = c - t * D_;
            int h = rem >> 6, dd = rem & 63;
            qkv[((size_t)((t * B_ + b_) * H_ + h) * N_ + n) * HD + dd] = v;
        }
    }
}

// ---------------------------------------------------------------------------
// K2: CholeskyQR per slab. blockIdx.x in [0,768): bit0 = t (0=q,1=k),
// rest = b*H+h. A is 256x64; G = A^T A (two 128-row chunks), U = chol(G),
// Q = A U^-1 written back in place. LDS: 128x68 + 64x68 = 52 KB.
// ---------------------------------------------------------------------------
__global__ __launch_bounds__(256) void k_cholqr(float* __restrict__ qkv) {
    const int blk = blockIdx.x;
    const int t = blk & 1;
    const int slab = blk >> 1;           // b*H + h
    float* base = qkv + (size_t)(t * BH + slab) * SLAB;

    __shared__ float As[128][68];
    __shared__ float G[64][68];
    const int tid = threadIdx.x;
    const int gi = tid >> 2;             // 0..63
    const int gj0 = (tid & 3) * 16;      // 0,16,32,48

    float sums[16];
#pragma unroll
    for (int j = 0; j < 16; j++) sums[j] = 0.f;

    // --- G = A^T A over two 128-row chunks ---
    for (int ch = 0; ch < 2; ch++) {
        __syncthreads();
        for (int i = 0; i < 32; i++) {
            int off = i * 256 + tid;     // 0..8191
            As[off >> 6][off & 63] = base[ch * 8192 + off];
        }
        __syncthreads();
        for (int r = 0; r < 128; r++) {
            float a = As[r][gi];
            const float4* rowp = (const float4*)&As[r][gj0];
#pragma unroll
            for (int q4 = 0; q4 < 4; q4++) {
                float4 v4 = rowp[q4];
                sums[q4 * 4 + 0] += a * v4.x;
                sums[q4 * 4 + 1] += a * v4.y;
                sums[q4 * 4 + 2] += a * v4.z;
                sums[q4 * 4 + 3] += a * v4.w;
            }
        }
    }
#pragma unroll
    for (int j = 0; j < 16; j++) G[gi][gj0 + j] = sums[j];
    __syncthreads();

    // --- Cholesky (upper): G = U^T U ---
    for (int j = 0; j < 64; j++) {
        if (tid == 0) G[j][j] = sqrtf(G[j][j]);
        __syncthreads();
        if (tid < 64 && tid > j) G[j][tid] /= G[j][j];
        __syncthreads();
#pragma unroll
        for (int q = 0; q < 16; q++) {
            int cc = gj0 + q;
            if (gi > j && cc >= gi) G[gi][cc] -= G[j][gi] * G[j][cc];
        }
        __syncthreads();
    }

    // --- Q = A U^-1, in place, two 128-row chunks ---
    for (int ch = 0; ch < 2; ch++) {
        for (int i = 0; i < 32; i++) {
            int off = i * 256 + tid;
            As[off >> 6][off & 63] = base[ch * 8192 + off];
        }
        __syncthreads();
        if (tid < 128) {
            float* row = &As[tid][0];
            for (int c = 0; c < 64; c++) {
                float s = row[c];
                for (int i = 0; i < c; i++) s -= row[i] * G[i][c];
                row[c] = s / G[c][c];
            }
        }
        __syncthreads();
        for (int i = 0; i < 32; i++) {
            int off = i * 256 + tid;
            base[ch * 8192 + off] = As[off >> 6][off & 63];
        }
        __syncthreads();
    }
}

// ---------------------------------------------------------------------------
// K3: mixed[b,o,n,m] = sum_h w2[o,h]*(Qq[b,h,n,:].Qk[b,h,m,:])^2*scale + cb[o]
// block = (b, 32-row n tile, 32-col m tile); thread owns 4 consecutive m.
// ---------------------------------------------------------------------------
__global__ __launch_bounds__(256) void k_logits(const float* __restrict__ qkv,
                                                const float* __restrict__ conv_w,
                                                const float* __restrict__ conv_b,
                                                const float* __restrict__ gscale,
                                                float* __restrict__ mixed) {
    const int b = blockIdx.x;
    const int n0 = blockIdx.y * 32;
    const int m0 = blockIdx.z * 32;
    __shared__ float Qs[32][68];
    __shared__ float Ks[32][68];
    __shared__ float w2[12][12];
    __shared__ float cb[12];
    const int tid = threadIdx.x;
    if (tid < 144) {
        int o = tid / 12, h = tid - o * 12;
        w2[o][h] = conv_w[o * 24 + h] + conv_w[o * 24 + 12 + h];
    }
    if (tid < 12) cb[tid] = conv_b[tid];
    const float scale = gscale[0];
    const int nl = tid >> 3;          // 0..31
    const int ml = (tid & 7) * 4;     // 0,4,...,28
    float acc[4][12] = {};

    for (int h = 0; h < 12; h++) {
        const float* qb = qkv + ((size_t)(b * H_ + h) * N_ + n0) * HD;
        const float* kb = qkv + ((size_t)(BH + b * H_ + h) * N_ + m0) * HD;
        __syncthreads();
#pragma unroll
        for (int i = 0; i < 8; i++) {
            int off = i * 256 + tid;      // 0..2047 -> row=off>>6, col=off&63
            Qs[off >> 6][off & 63] = qb[off];
            Ks[off >> 6][off & 63] = kb[off];
        }
        __syncthreads();

        const float4* qrow = (const float4*)&Qs[nl][0];
        const float4* k0p = (const float4*)&Ks[ml + 0][0];
        const float4* k1p = (const float4*)&Ks[ml + 1][0];
        const float4* k2p = (const float4*)&Ks[ml + 2][0];
        const float4* k3p = (const float4*)&Ks[ml + 3][0];
        float d0 = 0.f, d1 = 0.f, d2 = 0.f, d3 = 0.f;
#pragma unroll
        for (int c4 = 0; c4 < 16; c4++) {
            float4 a = qrow[c4];
            float4 x0 = k0p[c4], x1 = k1p[c4], x2 = k2p[c4], x3 = k3p[c4];
            d0 += a.x * x0.x + a.y * x0.y + a.z * x0.z + a.w * x0.w;
            d1 += a.x * x1.x + a.y * x1.y + a.z * x1.z + a.w * x1.w;
            d2 += a.x * x2.x + a.y * x2.y + a.z * x2.z + a.w * x2.w;
            d3 += a.x * x3.x + a.y * x3.y + a.z * x3.z + a.w * x3.w;
        }
        float g0 = d0 * d0 * scale, g1 = d1 * d1 * scale;
        float g2 = d2 * d2 * scale, g3 = d3 * d3 * scale;
#pragma unroll
        for (int o = 0; o < 12; o++) {
            float wv = w2[o][h];
            acc[0][o] += wv * g0;
            acc[1][o] += wv * g1;
            acc[2][o] += wv * g2;
            acc[3][o] += wv * g3;
        }
    }

#pragma unroll
    for (int o = 0; o < 12; o++) {
        float cbo = cb[o];
        float4 vv = make_float4(acc[0][o] + cbo, acc[1][o] + cbo,
                                acc[2][o] + cbo, acc[3][o] + cbo);
        *(float4*)&mixed[((size_t)(b * H_ + o) * N_ + (n0 + nl)) * N_ + m0 + ml] = vv;
    }
}

// ---------------------------------------------------------------------------
// K4: softmax over last dim (256), one block per row, in place.
// ---------------------------------------------------------------------------
__global__ __launch_bounds__(256) void k_softmax(float* __restrict__ p) {
    size_t base = (size_t)blockIdx.x * 256;
    const int tid = threadIdx.x;
    const int lane = tid & 63, wv = tid >> 6;
    __shared__ float red[8];
    float x = p[base + tid];
    float m = x;
#pragma unroll
    for (int off = 32; off; off >>= 1) m = fmaxf(m, __shfl_down(m, off, 64));
    if (lane == 0) red[wv] = m;
    __syncthreads();
    m = fmaxf(fmaxf(red[0], red[1]), fmaxf(red[2], red[3]));
    float e = __expf(x - m);
    float s = e;
#pragma unroll
    for (int off = 32; off; off >>= 1) s += __shfl_down(s, off, 64);
    if (lane == 0) red[4 + wv] = s;
    __syncthreads();
    s = red[4] + red[5] + red[6] + red[7];
    p[base + tid] = e / s;
}

// ---------------------------------------------------------------------------
// K5: aout[b, n, o*64+dd] = sum_m attn[b,o,n,m] * v[b,o,m,dd]
// block = (b, o, 64-row n tile); 4x4 per thread; m chunks of 32.
// ---------------------------------------------------------------------------
__global__ __launch_bounds__(256) void k_av(const float* __restrict__ attn,
                                            const float* __restrict__ qkv,
                                            float* __restrict__ aout) {
    const int b = blockIdx.x, o = blockIdx.y, n0 = blockIdx.z * 64;
    __shared__ float Ps[64][33];
    __shared__ float Vs[32][68];
    const int tid = threadIdx.x;
    const int ty = tid >> 4, tx = tid & 15;
    float acc[4][4] = {};
    const float* abase = attn + ((size_t)(b * H_ + o) * N_ + n0) * N_;
    const float* vbase = qkv + (size_t)(2 * BH + b * H_ + o) * SLAB;

    for (int m0 = 0; m0 < 256; m0 += 32) {
        __syncthreads();
#pragma unroll
        for (int i = 0; i < 8; i++) {
            int e = i * 256 + tid;  // 0..2047
            int r = e >> 5, c = e & 31;
            Ps[r][c] = abase[(size_t)r * 256 + m0 + c];
            int r2 = e >> 6, c2 = e & 63;
            Vs[r2][c2] = vbase[(size_t)(m0 + r2) * 64 + c2];
        }
        __syncthreads();
#pragma unroll
        for (int mm = 0; mm < 32; mm++) {
            float p0 = Ps[ty * 4 + 0][mm];
            float p1 = Ps[ty * 4 + 1][mm];
            float p2 = Ps[ty * 4 + 2][mm];
            float p3 = Ps[ty * 4 + 3][mm];
            float4 v4 = *(const float4*)&Vs[mm][tx * 4];
            acc[0][0] += p0 * v4.x; acc[0][1] += p0 * v4.y; acc[0][2] += p0 * v4.z; acc[0][3] += p0 * v4.w;
            acc[1][0] += p1 * v4.x; acc[1][1] += p1 * v4.y; acc[1][2] += p1 * v4.z; acc[1][3] += p1 * v4.w;
            acc[2][0] += p2 * v4.x; acc[2][1] += p2 * v4.y; acc[2][2] += p2 * v4.z; acc[2][3] += p2 * v4.w;
            acc[3][0] += p3 * v4.x; acc[3][1] += p3 * v4.y; acc[3][2] += p3 * v4.z; acc[3][3] += p3 * v4.w;
        }
    }

#pragma unroll
    for (int i = 0; i < 4; i++) {
        float4 vv = make_float4(acc[i][0], acc[i][1], acc[i][2], acc[i][3]);
        *(float4*)&aout[((size_t)(b * N_) + n0 + ty * 4 + i) * D_ + o * HD + tx * 4] = vv;
    }
}

// ---------------------------------------------------------------------------
// K6: out = aout @ proj_w^T + proj_b   (8192 x 768 x 768)
// ---------------------------------------------------------------------------
__global__ __launch_bounds__(256) void k_proj(const float* __restrict__ a_in,
                                              const float* __restrict__ w,
                                              const float* __restrict__ bias,
                                              float* __restrict__ out) {
    __shared__ float As[128][17];
    __shared__ float Bs[128][17];
    const int tid = threadIdx.x;
    const int r0 = blockIdx.x * 128;
    const int c0 = blockIdx.y * 128;
    const int ty = tid >> 4, tx = tid & 15;
    float acc[8][8] = {};

    for (int k0 = 0; k0 < D_; k0 += 16) {
#pragma unroll
        for (int i = 0; i < 8; i++) {
            int e = i * 256 + tid;
            int row = e >> 4, kk = e & 15;
            As[row][kk] = a_in[(size_t)(r0 + row) * D_ + k0 + kk];
            Bs[row][kk] = w[(size_t)(c0 + row) * D_ + k0 + kk];
        }
        __syncthreads();
#pragma unroll
        for (int kk = 0; kk < 16; kk++) {
            float a[8], b[8];
#pragma unroll
            for (int i = 0; i < 8; i++) a[i] = As[ty * 8 + i][kk];
#pragma unroll
            for (int j = 0; j < 8; j++) b[j] = Bs[tx * 8 + j][kk];
#pragma unroll
            for (int i = 0; i < 8; i++)
#pragma unroll
                for (int j = 0; j < 8; j++) acc[i][j] += a[i] * b[j];
        }
        __syncthreads();
    }

#pragma unroll
    for (int i = 0; i < 8; i++) {
        int r = r0 + ty * 8 + i;
#pragma unroll
        for (int j = 0; j < 8; j++) {
            int c = c0 + tx * 8 + j;
            out[(size_t)r * D_ + c] = acc[i][j] + bias[c];
        }
    }
}

// ---------------------------------------------------------------------------
extern "C" void kernel_launch(void* const* d_in, const int* in_sizes, int n_in,
                              void* d_out, int out_size, void* d_ws, size_t ws_size,
                              hipStream_t stream) {
    const float* x      = (const float*)d_in[0];
    const float* qkv_w  = (const float*)d_in[1];
    const float* qkv_b  = (const float*)d_in[2];
    const float* gscale = (const float*)d_in[3];
    const float* conv_w = (const float*)d_in[4];
    const float* conv_b = (const float*)d_in[5];
    const float* proj_w = (const float*)d_in[6];
    const float* proj_b = (const float*)d_in[7];

    float* ws    = (float*)d_ws;
    float* qkv   = ws;                       // 3*B*H*N*d = 18,874,368 floats
    float* mixed = ws + 18874368;            // B*H*N*N   = 25,165,824 floats
    float* aout  = ws;                       // reuse q slot (dead after K3): 6,291,456 floats
    float* out   = (float*)d_out;

    // K1: qkv projection
    hipLaunchKernelGGL(k_qkv_gemm, dim3(64, 18), dim3(256), 0, stream,
                       x, qkv_w, qkv_b, qkv);
    // K2: CholeskyQR of q and k slabs (768 slabs)
    hipLaunchKernelGGL(k_cholqr, dim3(768), dim3(256), 0, stream, qkv);
    // K3: squared-dot logits + channel mix
    hipLaunchKernelGGL(k_logits, dim3(32, 8, 8), dim3(256), 0, stream,
                       qkv, conv_w, conv_b, gscale, mixed);
    // K4: softmax over m
    hipLaunchKernelGGL(k_softmax, dim3(BH * N_), dim3(256), 0, stream, mixed);
    // K5: attn @ v -> (B,N,C)
    hipLaunchKernelGGL(k_av, dim3(32, 12, 4), dim3(256), 0, stream,
                       mixed, qkv, aout);
    // K6: output projection
    hipLaunchKernelGGL(k_proj, dim3(64, 6), dim3(256), 0, stream,
                       aout, proj_w, proj_b, out);
}

// Round 2
// 686.998 us; speedup vs baseline: 2.0802x; 2.0802x over previous
//
#include <hip/hip_runtime.h>
#include <hip/hip_bf16.h>

// RiemGrassAtt — round 2: bf16 MFMA for the two dense GEMMs.
// Shapes: B=32, N=256, H=12, d=64, D=768.
//   K0a cvt x->bf16, qkv_w->bf16 (into dead `mixed` region)
//   K1  qkv GEMM (29 GFLOP) via mfma_f32_16x16x32_bf16 -> q,k,v fp32 (t,B,H,N,d)
//   K2  CholeskyQR per (t,b,h) slab (fp32, unchanged)
//   K3  logits: mixed = sum_h w2[o,h]*(Qq.Qk)^2*scale + cb  (fp32, unchanged)
//   K4  row softmax (unchanged)
//   K0b cvt proj_w->bf16 (into dead k slot)
//   K5  attn @ v -> aout bf16 (B,N,C) (q slot, dead after K3)
//   K6  proj GEMM (9.7 GFLOP) via MFMA -> d_out fp32

#define B_   32
#define N_   256
#define H_   12
#define D_   768
#define HD   64
#define SLAB (N_ * HD)   // 16384
#define BH   (B_ * H_)   // 384

typedef unsigned int u32;
typedef __bf16 bf16x8 __attribute__((ext_vector_type(8)));
typedef float f32x4 __attribute__((ext_vector_type(4)));
typedef const u32 __attribute__((address_space(1)))* gptr_t;
typedef u32 __attribute__((address_space(3)))* lptr_t;

__device__ __forceinline__ u32 f2bf(float f) {
    u32 u = __builtin_bit_cast(u32, f);
    return (u + 0x7fffu + ((u >> 16) & 1u)) >> 16;   // RNE
}

// ---------------------------------------------------------------------------
// fp32 -> bf16 converter (float4 -> 4x bf16 per thread)
// ---------------------------------------------------------------------------
__global__ __launch_bounds__(256) void k_cvt(const float* __restrict__ src,
                                             unsigned short* __restrict__ dst,
                                             int n4) {
    int i = blockIdx.x * 256 + threadIdx.x;
    if (i >= n4) return;
    float4 v = ((const float4*)src)[i];
    u32 lo = f2bf(v.x) | (f2bf(v.y) << 16);
    u32 hi = f2bf(v.z) | (f2bf(v.w) << 16);
    ((uint2*)dst)[i] = make_uint2(lo, hi);
}

// ---------------------------------------------------------------------------
// Shared MFMA GEMM core: C(128x128 tile) = A(Mx768) @ B(Nx768)^T, bf16 in,
// fp32 acc. 256 threads = 4 waves in 2x2; each wave 64x64 = 4x4 of 16x16x32.
// Staging: global_load_lds width=16, XOR-swizzle (chunk ^= row&7) so the
// ds_read_b128 fragment reads are <=2-way bank conflicted (free).
// ---------------------------------------------------------------------------
__device__ __forceinline__ void mfma_gemm_core(const unsigned short* __restrict__ A,
                                               const unsigned short* __restrict__ Bm,
                                               int r0, int c0, int tid,
                                               unsigned short* As, unsigned short* Bs,
                                               f32x4 acc[4][4]) {
    const int lane = tid & 63;
    const int wid = tid >> 6;
    const int wm = (wid >> 1) * 64, wn = (wid & 1) * 64;
    const int lrow = lane >> 3;                 // 0..7 within an 8-row group
    const int lchunk = (lane & 7) ^ lrow;       // XOR-swizzled source chunk

    for (int k0 = 0; k0 < 768; k0 += 64) {
#pragma unroll
        for (int i = 0; i < 4; i++) {
            int row = i * 32 + wid * 8 + lrow;  // tile-local row, r&7 == lrow
            const unsigned short* ga = A + (size_t)(r0 + row) * 768 + k0 + lchunk * 8;
            const unsigned short* gb = Bm + (size_t)(c0 + row) * 768 + k0 + lchunk * 8;
            __builtin_amdgcn_global_load_lds((gptr_t)(const void*)ga,
                                             (lptr_t)(void*)(As + (i * 32 + wid * 8) * 64),
                                             16, 0, 0);
            __builtin_amdgcn_global_load_lds((gptr_t)(const void*)gb,
                                             (lptr_t)(void*)(Bs + (i * 32 + wid * 8) * 64),
                                             16, 0, 0);
        }
        __syncthreads();
#pragma unroll
        for (int s = 0; s < 2; s++) {
            bf16x8 af[4], bfr[4];
#pragma unroll
            for (int mi = 0; mi < 4; mi++) {
                int ra = wm + mi * 16 + (lane & 15);
                int pa = ((lane >> 4) + s * 4) ^ (ra & 7);
                af[mi] = *(const bf16x8*)(As + ra * 64 + pa * 8);
                int rb = wn + mi * 16 + (lane & 15);
                int pb = ((lane >> 4) + s * 4) ^ (rb & 7);
                bfr[mi] = *(const bf16x8*)(Bs + rb * 64 + pb * 8);
            }
#pragma unroll
            for (int mi = 0; mi < 4; mi++)
#pragma unroll
                for (int ni = 0; ni < 4; ni++)
                    acc[mi][ni] = __builtin_amdgcn_mfma_f32_16x16x32_bf16(
                        af[mi], bfr[ni], acc[mi][ni], 0, 0, 0);
        }
        __syncthreads();
    }
}

// ---------------------------------------------------------------------------
// K1: qkv = x @ qkv_w^T + qkv_b, scattered fp32 into (3,B,H,N,d)
// ---------------------------------------------------------------------------
__global__ __launch_bounds__(256) void k_qkv_mfma(const unsigned short* __restrict__ x_bf,
                                                  const unsigned short* __restrict__ w_bf,
                                                  const float* __restrict__ bias,
                                                  float* __restrict__ qkv) {
    __shared__ unsigned short As[128 * 64];
    __shared__ unsigned short Bs[128 * 64];
    const int tid = threadIdx.x;
    const int r0 = blockIdx.x * 128;
    const int c0 = blockIdx.y * 128;
    const int lane = tid & 63;
    const int wid = tid >> 6;
    const int wm = (wid >> 1) * 64, wn = (wid & 1) * 64;
    f32x4 acc[4][4] = {};

    mfma_gemm_core(x_bf, w_bf, r0, c0, tid, As, Bs, acc);

    const int t = c0 / D_;              // block-uniform (128 | 768)
    float bias4[4];
#pragma unroll
    for (int ni = 0; ni < 4; ni++) bias4[ni] = bias[c0 + wn + ni * 16 + (lane & 15)];

#pragma unroll
    for (int mi = 0; mi < 4; mi++) {
#pragma unroll
        for (int i = 0; i < 4; i++) {
            int gr = r0 + wm + mi * 16 + (lane >> 4) * 4 + i;
            int b_ = gr >> 8, n = gr & 255;
#pragma unroll
            for (int ni = 0; ni < 4; ni++) {
                int gc = c0 + wn + ni * 16 + (lane & 15);
                int rem = gc - t * D_;
                int h = rem >> 6, dd = rem & 63;
                qkv[((size_t)((t * B_ + b_) * H_ + h) * N_ + n) * HD + dd] =
                    acc[mi][ni][i] + bias4[ni];
            }
        }
    }
}

// ---------------------------------------------------------------------------
// K6: out = aout_bf @ pw_bf^T + proj_b  (8192 x 768 x 768), fp32 out
// ---------------------------------------------------------------------------
__global__ __launch_bounds__(256) void k_proj_mfma(const unsigned short* __restrict__ a_bf,
                                                   const unsigned short* __restrict__ w_bf,
                                                   const float* __restrict__ bias,
                                                   float* __restrict__ out) {
    __shared__ unsigned short As[128 * 64];
    __shared__ unsigned short Bs[128 * 64];
    const int tid = threadIdx.x;
    const int r0 = blockIdx.x * 128;
    const int c0 = blockIdx.y * 128;
    const int lane = tid & 63;
    const int wid = tid >> 6;
    const int wm = (wid >> 1) * 64, wn = (wid & 1) * 64;
    f32x4 acc[4][4] = {};

    mfma_gemm_core(a_bf, w_bf, r0, c0, tid, As, Bs, acc);

    float bias4[4];
#pragma unroll
    for (int ni = 0; ni < 4; ni++) bias4[ni] = bias[c0 + wn + ni * 16 + (lane & 15)];

#pragma unroll
    for (int mi = 0; mi < 4; mi++) {
#pragma unroll
        for (int i = 0; i < 4; i++) {
            int gr = r0 + wm + mi * 16 + (lane >> 4) * 4 + i;
#pragma unroll
            for (int ni = 0; ni < 4; ni++) {
                int gc = c0 + wn + ni * 16 + (lane & 15);
                out[(size_t)gr * D_ + gc] = acc[mi][ni][i] + bias4[ni];
            }
        }
    }
}

// ---------------------------------------------------------------------------
// K2: CholeskyQR per slab (unchanged from round 1)
// ---------------------------------------------------------------------------
__global__ __launch_bounds__(256) void k_cholqr(float* __restrict__ qkv) {
    const int blk = blockIdx.x;
    const int t = blk & 1;
    const int slab = blk >> 1;
    float* base = qkv + (size_t)(t * BH + slab) * SLAB;

    __shared__ float Asq[128][68];
    __shared__ float G[64][68];
    const int tid = threadIdx.x;
    const int gi = tid >> 2;
    const int gj0 = (tid & 3) * 16;

    float sums[16];
#pragma unroll
    for (int j = 0; j < 16; j++) sums[j] = 0.f;

    for (int ch = 0; ch < 2; ch++) {
        __syncthreads();
        for (int i = 0; i < 32; i++) {
            int off = i * 256 + tid;
            Asq[off >> 6][off & 63] = base[ch * 8192 + off];
        }
        __syncthreads();
        for (int r = 0; r < 128; r++) {
            float a = Asq[r][gi];
            const float4* rowp = (const float4*)&Asq[r][gj0];
#pragma unroll
            for (int q4 = 0; q4 < 4; q4++) {
                float4 v4 = rowp[q4];
                sums[q4 * 4 + 0] += a * v4.x;
                sums[q4 * 4 + 1] += a * v4.y;
                sums[q4 * 4 + 2] += a * v4.z;
                sums[q4 * 4 + 3] += a * v4.w;
            }
        }
    }
#pragma unroll
    for (int j = 0; j < 16; j++) G[gi][gj0 + j] = sums[j];
    __syncthreads();

    for (int j = 0; j < 64; j++) {
        if (tid == 0) G[j][j] = sqrtf(G[j][j]);
        __syncthreads();
        if (tid < 64 && tid > j) G[j][tid] /= G[j][j];
        __syncthreads();
#pragma unroll
        for (int q = 0; q < 16; q++) {
            int cc = gj0 + q;
            if (gi > j && cc >= gi) G[gi][cc] -= G[j][gi] * G[j][cc];
        }
        __syncthreads();
    }

    for (int ch = 0; ch < 2; ch++) {
        for (int i = 0; i < 32; i++) {
            int off = i * 256 + tid;
            Asq[off >> 6][off & 63] = base[ch * 8192 + off];
        }
        __syncthreads();
        if (tid < 128) {
            float* row = &Asq[tid][0];
            for (int c = 0; c < 64; c++) {
                float s = row[c];
                for (int i = 0; i < c; i++) s -= row[i] * G[i][c];
                row[c] = s / G[c][c];
            }
        }
        __syncthreads();
        for (int i = 0; i < 32; i++) {
            int off = i * 256 + tid;
            base[ch * 8192 + off] = Asq[off >> 6][off & 63];
        }
        __syncthreads();
    }
}

// ---------------------------------------------------------------------------
// K3: logits (unchanged)
// ---------------------------------------------------------------------------
__global__ __launch_bounds__(256) void k_logits(const float* __restrict__ qkv,
                                                const float* __restrict__ conv_w,
                                                const float* __restrict__ conv_b,
                                                const float* __restrict__ gscale,
                                                float* __restrict__ mixed) {
    const int b = blockIdx.x;
    const int n0 = blockIdx.y * 32;
    const int m0 = blockIdx.z * 32;
    __shared__ float Qs[32][68];
    __shared__ float Ks[32][68];
    __shared__ float w2[12][12];
    __shared__ float cb[12];
    const int tid = threadIdx.x;
    if (tid < 144) {
        int o = tid / 12, h = tid - o * 12;
        w2[o][h] = conv_w[o * 24 + h] + conv_w[o * 24 + 12 + h];
    }
    if (tid < 12) cb[tid] = conv_b[tid];
    const float scale = gscale[0];
    const int nl = tid >> 3;
    const int ml = (tid & 7) * 4;
    float acc[4][12] = {};

    for (int h = 0; h < 12; h++) {
        const float* qb = qkv + ((size_t)(b * H_ + h) * N_ + n0) * HD;
        const float* kb = qkv + ((size_t)(BH + b * H_ + h) * N_ + m0) * HD;
        __syncthreads();
#pragma unroll
        for (int i = 0; i < 8; i++) {
            int off = i * 256 + tid;
            Qs[off >> 6][off & 63] = qb[off];
            Ks[off >> 6][off & 63] = kb[off];
        }
        __syncthreads();

        const float4* qrow = (const float4*)&Qs[nl][0];
        const float4* k0p = (const float4*)&Ks[ml + 0][0];
        const float4* k1p = (const float4*)&Ks[ml + 1][0];
        const float4* k2p = (const float4*)&Ks[ml + 2][0];
        const float4* k3p = (const float4*)&Ks[ml + 3][0];
        float d0 = 0.f, d1 = 0.f, d2 = 0.f, d3 = 0.f;
#pragma unroll
        for (int c4 = 0; c4 < 16; c4++) {
            float4 a = qrow[c4];
            float4 x0 = k0p[c4], x1 = k1p[c4], x2 = k2p[c4], x3 = k3p[c4];
            d0 += a.x * x0.x + a.y * x0.y + a.z * x0.z + a.w * x0.w;
            d1 += a.x * x1.x + a.y * x1.y + a.z * x1.z + a.w * x1.w;
            d2 += a.x * x2.x + a.y * x2.y + a.z * x2.z + a.w * x2.w;
            d3 += a.x * x3.x + a.y * x3.y + a.z * x3.z + a.w * x3.w;
        }
        float g0 = d0 * d0 * scale, g1 = d1 * d1 * scale;
        float g2 = d2 * d2 * scale, g3 = d3 * d3 * scale;
#pragma unroll
        for (int o = 0; o < 12; o++) {
            float wv = w2[o][h];
            acc[0][o] += wv * g0;
            acc[1][o] += wv * g1;
            acc[2][o] += wv * g2;
            acc[3][o] += wv * g3;
        }
    }

#pragma unroll
    for (int o = 0; o < 12; o++) {
        float cbo = cb[o];
        float4 vv = make_float4(acc[0][o] + cbo, acc[1][o] + cbo,
                                acc[2][o] + cbo, acc[3][o] + cbo);
        *(float4*)&mixed[((size_t)(b * H_ + o) * N_ + (n0 + nl)) * N_ + m0 + ml] = vv;
    }
}

// ---------------------------------------------------------------------------
// K4: softmax (unchanged)
// ---------------------------------------------------------------------------
__global__ __launch_bounds__(256) void k_softmax(float* __restrict__ p) {
    size_t base = (size_t)blockIdx.x * 256;
    const int tid = threadIdx.x;
    const int lane = tid & 63, wv = tid >> 6;
    __shared__ float red[8];
    float x = p[base + tid];
    float m = x;
#pragma unroll
    for (int off = 32; off; off >>= 1) m = fmaxf(m, __shfl_down(m, off, 64));
    if (lane == 0) red[wv] = m;
    __syncthreads();
    m = fmaxf(fmaxf(red[0], red[1]), fmaxf(red[2], red[3]));
    float e = __expf(x - m);
    float s = e;
#pragma unroll
    for (int off = 32; off; off >>= 1) s += __shfl_down(s, off, 64);
    if (lane == 0) red[4 + wv] = s;
    __syncthreads();
    s = red[4] + red[5] + red[6] + red[7];
    p[base + tid] = e / s;
}

// ---------------------------------------------------------------------------
// K5: aout_bf[b, n, o*64+dd] = bf16( sum_m attn[b,o,n,m] * v[b,o,m,dd] )
// ---------------------------------------------------------------------------
__global__ __launch_bounds__(256) void k_av(const float* __restrict__ attn,
                                            const float* __restrict__ qkv,
                                            unsigned short* __restrict__ aout) {
    const int b = blockIdx.x, o = blockIdx.y, n0 = blockIdx.z * 64;
    __shared__ float Ps[64][33];
    __shared__ float Vs[32][68];
    const int tid = threadIdx.x;
    const int ty = tid >> 4, tx = tid & 15;
    float acc[4][4] = {};
    const float* abase = attn + ((size_t)(b * H_ + o) * N_ + n0) * N_;
    const float* vbase = qkv + (size_t)(2 * BH + b * H_ + o) * SLAB;

    for (int m0 = 0; m0 < 256; m0 += 32) {
        __syncthreads();
#pragma unroll
        for (int i = 0; i < 8; i++) {
            int e = i * 256 + tid;
            int r = e >> 5, c = e & 31;
            Ps[r][c] = abase[(size_t)r * 256 + m0 + c];
            int r2 = e >> 6, c2 = e & 63;
            Vs[r2][c2] = vbase[(size_t)(m0 + r2) * 64 + c2];
        }
        __syncthreads();
#pragma unroll
        for (int mm = 0; mm < 32; mm++) {
            float p0 = Ps[ty * 4 + 0][mm];
            float p1 = Ps[ty * 4 + 1][mm];
            float p2 = Ps[ty * 4 + 2][mm];
            float p3 = Ps[ty * 4 + 3][mm];
            float4 v4 = *(const float4*)&Vs[mm][tx * 4];
            acc[0][0] += p0 * v4.x; acc[0][1] += p0 * v4.y; acc[0][2] += p0 * v4.z; acc[0][3] += p0 * v4.w;
            acc[1][0] += p1 * v4.x; acc[1][1] += p1 * v4.y; acc[1][2] += p1 * v4.z; acc[1][3] += p1 * v4.w;
            acc[2][0] += p2 * v4.x; acc[2][1] += p2 * v4.y; acc[2][2] += p2 * v4.z; acc[2][3] += p2 * v4.w;
            acc[3][0] += p3 * v4.x; acc[3][1] += p3 * v4.y; acc[3][2] += p3 * v4.z; acc[3][3] += p3 * v4.w;
        }
    }

#pragma unroll
    for (int i = 0; i < 4; i++) {
        u32 lo = f2bf(acc[i][0]) | (f2bf(acc[i][1]) << 16);
        u32 hi = f2bf(acc[i][2]) | (f2bf(acc[i][3]) << 16);
        size_t idx = ((size_t)(b * N_) + n0 + ty * 4 + i) * D_ + o * HD + tx * 4;
        *(uint2*)(aout + idx) = make_uint2(lo, hi);
    }
}

// ---------------------------------------------------------------------------
extern "C" void kernel_launch(void* const* d_in, const int* in_sizes, int n_in,
                              void* d_out, int out_size, void* d_ws, size_t ws_size,
                              hipStream_t stream) {
    const float* x      = (const float*)d_in[0];
    const float* qkv_w  = (const float*)d_in[1];
    const float* qkv_b  = (const float*)d_in[2];
    const float* gscale = (const float*)d_in[3];
    const float* conv_w = (const float*)d_in[4];
    const float* conv_b = (const float*)d_in[5];
    const float* proj_w = (const float*)d_in[6];
    const float* proj_b = (const float*)d_in[7];

    float* ws    = (float*)d_ws;
    float* qkv   = ws;                        // 18,874,368 f (q|k|v slots, 6,291,456 f each)
    float* mixed = ws + 18874368;             // 25,165,824 f
    // bf16 overlays in dead regions:
    unsigned short* x_bf    = (unsigned short*)mixed;       // dead until K3
    unsigned short* w_bf    = x_bf + 6291456;
    unsigned short* aout_bf = (unsigned short*)qkv;         // q slot, dead after K3
    unsigned short* pw_bf   = (unsigned short*)(qkv + 6291456); // k slot, dead after K3
    float* out   = (float*)d_out;

    // K0a: fp32 -> bf16 for x and qkv_w
    hipLaunchKernelGGL(k_cvt, dim3(6144), dim3(256), 0, stream, x, x_bf, 1572864);
    hipLaunchKernelGGL(k_cvt, dim3(1728), dim3(256), 0, stream, qkv_w, w_bf, 442368);
    // K1: qkv projection (MFMA)
    hipLaunchKernelGGL(k_qkv_mfma, dim3(64, 18), dim3(256), 0, stream,
                       x_bf, w_bf, qkv_b, qkv);
    // K2: CholeskyQR of q and k slabs
    hipLaunchKernelGGL(k_cholqr, dim3(768), dim3(256), 0, stream, qkv);
    // K3: squared-dot logits + channel mix
    hipLaunchKernelGGL(k_logits, dim3(32, 8, 8), dim3(256), 0, stream,
                       qkv, conv_w, conv_b, gscale, mixed);
    // K4: softmax over m
    hipLaunchKernelGGL(k_softmax, dim3(BH * N_), dim3(256), 0, stream, mixed);
    // K0b: fp32 -> bf16 for proj_w (into dead k slot)
    hipLaunchKernelGGL(k_cvt, dim3(576), dim3(256), 0, stream, proj_w, pw_bf, 147456);
    // K5: attn @ v -> (B,N,C) bf16
    hipLaunchKernelGGL(k_av, dim3(32, 12, 4), dim3(256), 0, stream,
                       mixed, qkv, aout_bf);
    // K6: output projection (MFMA)
    hipLaunchKernelGGL(k_proj_mfma, dim3(64, 6), dim3(256), 0, stream,
                       aout_bf, pw_bf, proj_b, out);
}